// Round 1
// baseline (190.651 us; speedup 1.0000x reference)
//
#include <hip/hip_runtime.h>
#include <math.h>

// Problem geometry (fixed by the reference)
#define BB 8
#define CC 256
#define HH 192
#define WW 192
#define HWSZ (HH * WW)        // 36864, divisible by 4
#define HW4  (HWSZ / 4)       // 9216 float4s per (b,c) slice
#define INTERNAL 16

// Kernel 1: per-(b,c) sum of squares over the spatial slice.
__global__ __launch_bounds__(256) void se_sumsq_kernel(
    const float* __restrict__ in, float* __restrict__ sumsq)
{
    const int bc = blockIdx.x;  // 0 .. B*C-1
    const float4* p = reinterpret_cast<const float4*>(in + (size_t)bc * HWSZ);

    float acc = 0.f;
    #pragma unroll 4
    for (int i = threadIdx.x; i < HW4; i += 256) {
        float4 v = p[i];
        acc += v.x * v.x + v.y * v.y + v.z * v.z + v.w * v.w;
    }

    // wave (64-lane) shuffle reduction
    for (int off = 32; off > 0; off >>= 1)
        acc += __shfl_down(acc, off, 64);

    __shared__ float lds[4];
    const int lane = threadIdx.x & 63;
    const int wave = threadIdx.x >> 6;
    if (lane == 0) lds[wave] = acc;
    __syncthreads();
    if (threadIdx.x == 0)
        sumsq[bc] = lds[0] + lds[1] + lds[2] + lds[3];
}

// Kernel 2: tiny — per batch: x = Gx/(Gx+eps); h = relu(x@Wd^T+bd);
// gate = sigmoid(h@Wu^T+bu). One block per batch, 256 threads (=C).
__global__ __launch_bounds__(256) void se_gate_kernel(
    const float* __restrict__ sumsq,
    const float* __restrict__ w_down,  // [16, 256]
    const float* __restrict__ b_down,  // [16]
    const float* __restrict__ w_up,    // [256, 16]
    const float* __restrict__ b_up,    // [256]
    float* __restrict__ gate)          // [B, C]
{
    const int b = blockIdx.x;
    const int c = threadIdx.x;

    __shared__ float xs[CC];
    __shared__ float hs[INTERNAL];

    float g = sqrtf(sumsq[b * CC + c]);
    xs[c] = g / (g + 1e-6f);
    __syncthreads();

    if (c < INTERNAL) {
        float a = b_down[c];
        const float* wr = w_down + c * CC;
        for (int k = 0; k < CC; ++k) a += xs[k] * wr[k];
        hs[c] = fmaxf(a, 0.f);
    }
    __syncthreads();

    float a = b_up[c];
    const float* wu = w_up + c * INTERNAL;
    #pragma unroll
    for (int j = 0; j < INTERNAL; ++j) a += hs[j] * wu[j];
    gate[b * CC + c] = 1.f / (1.f + expf(-a));
}

// Kernel 3: out = in * gate[bc], broadcast over the spatial slice.
__global__ __launch_bounds__(256) void se_scale_kernel(
    const float* __restrict__ in, const float* __restrict__ gate,
    float* __restrict__ out)
{
    const int bc = blockIdx.x;
    const float gv = gate[bc];
    const float4* pi = reinterpret_cast<const float4*>(in + (size_t)bc * HWSZ);
    float4* po = reinterpret_cast<float4*>(out + (size_t)bc * HWSZ);

    #pragma unroll 4
    for (int i = threadIdx.x; i < HW4; i += 256) {
        float4 v = pi[i];
        v.x *= gv; v.y *= gv; v.z *= gv; v.w *= gv;
        po[i] = v;
    }
}

extern "C" void kernel_launch(void* const* d_in, const int* in_sizes, int n_in,
                              void* d_out, int out_size, void* d_ws, size_t ws_size,
                              hipStream_t stream) {
    const float* inputs = (const float*)d_in[0];   // [B, C, H, W]
    const float* w_down = (const float*)d_in[1];   // [16, 256]
    const float* b_down = (const float*)d_in[2];   // [16]
    const float* w_up   = (const float*)d_in[3];   // [256, 16]
    const float* b_up   = (const float*)d_in[4];   // [256]
    float* out = (float*)d_out;

    float* sumsq = (float*)d_ws;            // B*C floats
    float* gate  = sumsq + BB * CC;         // B*C floats

    const int nbc = BB * CC;  // 2048

    se_sumsq_kernel<<<nbc, 256, 0, stream>>>(inputs, sumsq);
    se_gate_kernel<<<BB, 256, 0, stream>>>(sumsq, w_down, b_down, w_up, b_up, gate);
    se_scale_kernel<<<nbc, 256, 0, stream>>>(inputs, gate, out);
}

// Round 2
// 186.882 us; speedup vs baseline: 1.0202x; 1.0202x over previous
//
#include <hip/hip_runtime.h>
#include <math.h>

// Problem geometry (fixed by the reference)
#define BB 8
#define CC 256
#define HH 192
#define WW 192
#define HWSZ (HH * WW)        // 36864 floats per (b,c) slice
#define HW4  (HWSZ / 4)       // 9216 float4
#define NPART 4               // blocks per (b,c) slice
#define Q4 (HW4 / NPART)      // 2304 float4 per part-block
#define ITERS (Q4 / 256)      // 9
#define INTERNAL 16

// ---- sum-of-squares for one quarter of one (b,c) slice ----
__device__ __forceinline__ void do_sumsq(const float* __restrict__ in,
                                         float* __restrict__ partials,
                                         int b, int idx, int tid)
{
    const int c = idx >> 2, part = idx & 3;
    const float4* p = reinterpret_cast<const float4*>(
        in + (size_t)(b * CC + c) * HWSZ) + part * Q4;

    float acc = 0.f;
    #pragma unroll
    for (int i = 0; i < ITERS; ++i) {
        float4 v = p[tid + i * 256];
        acc += v.x * v.x + v.y * v.y + v.z * v.z + v.w * v.w;
    }
    for (int off = 32; off > 0; off >>= 1)
        acc += __shfl_down(acc, off, 64);

    __shared__ float lds[4];
    const int lane = tid & 63, wave = tid >> 6;
    if (lane == 0) lds[wave] = acc;
    __syncthreads();
    if (tid == 0)
        partials[(size_t)(b * CC + c) * 4 + part] =
            lds[0] + lds[1] + lds[2] + lds[3];
}

// ---- gate (computed in-block from partials) + scale for one quarter slice ----
__device__ __forceinline__ void do_scale(const float* __restrict__ in,
                                         float* __restrict__ out,
                                         const float* __restrict__ partials,
                                         const float* __restrict__ w_down,
                                         const float* __restrict__ b_down,
                                         const float* __restrict__ w_up,
                                         const float* __restrict__ b_up,
                                         int b, int idx, int tid)
{
    const int c = idx >> 2, part = idx & 3;

    __shared__ float xs[CC];
    __shared__ float hs[INTERNAL];
    __shared__ float gshared;

    // x[k] = sqrt(ss)/(sqrt(ss)+eps) for all 256 channels of batch b
    {
        float4 pp = reinterpret_cast<const float4*>(
            partials + (size_t)b * CC * 4)[tid];
        float g = sqrtf(pp.x + pp.y + pp.z + pp.w);
        xs[tid] = g / (g + 1e-6f);
    }
    __syncthreads();

    // h[j] = relu(b_down[j] + sum_k x[k]*w_down[j][k]); 16 threads per j
    {
        const int j = tid >> 4, l = tid & 15;
        float a = 0.f;
        const float* wr = w_down + j * CC;
        #pragma unroll
        for (int k = 0; k < CC / 16; ++k)
            a += xs[l + k * 16] * wr[l + k * 16];
        // reduce across the 16-lane subgroup
        a += __shfl_down(a, 8, 16);
        a += __shfl_down(a, 4, 16);
        a += __shfl_down(a, 2, 16);
        a += __shfl_down(a, 1, 16);
        if (l == 0) hs[j] = fmaxf(a + b_down[j], 0.f);
    }
    __syncthreads();

    // gate scalar for this block's channel c
    if (tid == 0) {
        float a = b_up[c];
        const float* wu = w_up + c * INTERNAL;
        #pragma unroll
        for (int j = 0; j < INTERNAL; ++j) a += hs[j] * wu[j];
        gshared = 1.f / (1.f + expf(-a));
    }
    __syncthreads();

    const float gv = gshared;
    const float4* pi = reinterpret_cast<const float4*>(
        in + (size_t)(b * CC + c) * HWSZ) + part * Q4;
    float4* po = reinterpret_cast<float4*>(
        out + (size_t)(b * CC + c) * HWSZ) + part * Q4;

    #pragma unroll
    for (int i = 0; i < ITERS; ++i) {
        float4 v = pi[tid + i * 256];
        v.x *= gv; v.y *= gv; v.z *= gv; v.w *= gv;
        po[tid + i * 256] = v;
    }
}

// Combined pipelined kernel: blocks [0,1024) scale batch `scale_b`
// (L3-resident from the previous launch); blocks [1024,2048) sumsq batch
// `sum_b` (fresh HBM read). Either role may be absent (-1).
__global__ __launch_bounds__(256) void se_pipe_kernel(
    const float* __restrict__ in, float* __restrict__ out,
    float* __restrict__ partials,
    const float* __restrict__ w_down, const float* __restrict__ b_down,
    const float* __restrict__ w_up, const float* __restrict__ b_up,
    int scale_b, int sum_b)
{
    const int idx = blockIdx.x;
    const int tid = threadIdx.x;
    if (scale_b >= 0 && sum_b >= 0) {
        if (idx < CC * NPART)
            do_scale(in, out, partials, w_down, b_down, w_up, b_up,
                     scale_b, idx, tid);
        else
            do_sumsq(in, partials, sum_b, idx - CC * NPART, tid);
    } else if (sum_b >= 0) {
        do_sumsq(in, partials, sum_b, idx, tid);
    } else {
        do_scale(in, out, partials, w_down, b_down, w_up, b_up,
                 scale_b, idx, tid);
    }
}

extern "C" void kernel_launch(void* const* d_in, const int* in_sizes, int n_in,
                              void* d_out, int out_size, void* d_ws, size_t ws_size,
                              hipStream_t stream) {
    const float* inputs = (const float*)d_in[0];   // [B, C, H, W]
    const float* w_down = (const float*)d_in[1];   // [16, 256]
    const float* b_down = (const float*)d_in[2];   // [16]
    const float* w_up   = (const float*)d_in[3];   // [256, 16]
    const float* b_up   = (const float*)d_in[4];   // [256]
    float* out = (float*)d_out;

    float* partials = (float*)d_ws;  // [B*C][4] = 32 KB

    const int nqb = CC * NPART;  // 1024 blocks per role

    // prologue: sumsq(batch 0)
    se_pipe_kernel<<<nqb, 256, 0, stream>>>(
        inputs, out, partials, w_down, b_down, w_up, b_up, -1, 0);
    // steady state: scale(b) [L3 hit] + sumsq(b+1) [HBM]
    for (int b = 0; b < BB - 1; ++b)
        se_pipe_kernel<<<2 * nqb, 256, 0, stream>>>(
            inputs, out, partials, w_down, b_down, w_up, b_up, b, b + 1);
    // epilogue: scale(batch 7)
    se_pipe_kernel<<<nqb, 256, 0, stream>>>(
        inputs, out, partials, w_down, b_down, w_up, b_up, BB - 1, -1);
}